// Round 7
// baseline (1175.998 us; speedup 1.0000x reference)
//
#include <hip/hip_runtime.h>

// GCN 3-layer, CSR-free, two-pass edge sort + per-layer LDS accumulate.
// Math per layer (input u): z = u*dinv; s_i = sum_{e:dst=i} z[src_e];
//   out_i = (dinv_i*(s_i + z_i)) @ W + b   (self-loop folds into s+z).
// Pass A sorts edges by src>>13 (62 windows): pkA=(dst<<13)|(src&8191) (32b,
//   src-high implied by segment). Pass B scatters pkA into dst buckets of 1024
//   (pk32=(dst&1023)|(src<<10)); because pkA is src-sorted, pk32 within each
//   dst bucket ascends in src at 8K granularity -> layer gathers sweep z
//   sequentially (128KB windows, all 489 blocks in lockstep, z traffic ~8MB/XCD
//   instead of R6's 545MB random-gather fabric traffic on layer2).
// Both scatters: 512 blocks x consecutive tiles (bounded write set -> full-line
// write-back). Layers: LDS fp32 acc, stride 3/5 padding (banks (3d+c)%32
// uniform -> 0 conflicts, verified R6). N < 2^19.

#define TPB 256
#define T_TILE 8192
#define NPB 1024
#define NPB_BITS 10
#define SRCB_BITS 13
#define SRCW (1 << SRCB_BITS)

// ---------------- pass A: bucket by src window ----------------

__global__ void tilecountA(const int* __restrict__ src, int* __restrict__ cntA,
                           int ntA, int E, int SB) {
    __shared__ int hist[64];
    int blk = blockIdx.x, tid = threadIdx.x;
    if (tid < 64) hist[tid] = 0;
    __syncthreads();
    int base = blk * T_TILE;
    #pragma unroll 4
    for (int it = 0; it < T_TILE / 256; ++it) {
        int e = base + it * 256 + tid;
        if (e < E) atomicAdd(&hist[((unsigned)src[e]) >> SRCB_BITS], 1);
    }
    __syncthreads();
    if (tid < SB) cntA[(size_t)tid * ntA + blk] = hist[tid];
}

// ---- 3-kernel exclusive scan over data[len] (in-place), 1024 elems/block ----
__global__ void scan_k1(const int* __restrict__ data, int* __restrict__ bsum, int len) {
    __shared__ int lds[TPB];
    int b = blockIdx.x, t = threadIdx.x;
    int base = b * 1024 + t * 4;
    int s = 0;
    #pragma unroll
    for (int j = 0; j < 4; ++j) { int i = base + j; if (i < len) s += data[i]; }
    lds[t] = s; __syncthreads();
    for (int off = 128; off > 0; off >>= 1) {
        if (t < off) lds[t] += lds[t + off];
        __syncthreads();
    }
    if (t == 0) bsum[b] = lds[0];
}

__global__ void scan_k2(int* __restrict__ bsum, int NB) {
    __shared__ int lds[1024];
    int t = threadIdx.x;
    int v = (t < NB) ? bsum[t] : 0;
    lds[t] = v; __syncthreads();
    for (int off = 1; off < 1024; off <<= 1) {
        int add = (t >= off) ? lds[t - off] : 0;
        __syncthreads();
        lds[t] += add;
        __syncthreads();
    }
    if (t < NB) bsum[t] = lds[t] - v;  // exclusive
}

__global__ void scan_k3(int* __restrict__ data, const int* __restrict__ bsum, int len) {
    __shared__ int lds[TPB];
    int b = blockIdx.x, t = threadIdx.x;
    int base = b * 1024 + t * 4;
    int v[4]; int s = 0;
    #pragma unroll
    for (int j = 0; j < 4; ++j) { int i = base + j; v[j] = (i < len) ? data[i] : 0; s += v[j]; }
    int orig = s;
    lds[t] = s; __syncthreads();
    for (int off = 1; off < 256; off <<= 1) {
        int add = (t >= off) ? lds[t - off] : 0;
        __syncthreads();
        lds[t] += add;
        __syncthreads();
    }
    int run = bsum[b] + lds[t] - orig;
    #pragma unroll
    for (int j = 0; j < 4; ++j) {
        int i = base + j;
        if (i < len) { data[i] = run; run += v[j]; }
    }
}

__global__ void scatterA(const int* __restrict__ src, const int* __restrict__ dst,
                         const int* __restrict__ cntA, unsigned* __restrict__ pkA,
                         int ntA, int E, int SB, int tilesPerBlk) {
    __shared__ int basec[64];
    int tid = threadIdx.x;
    int t0 = blockIdx.x * tilesPerBlk;
    for (int tt = 0; tt < tilesPerBlk; ++tt) {
        int tile = t0 + tt;
        if (tile >= ntA) return;
        if (tid < SB) basec[tid] = cntA[(size_t)tid * ntA + tile];
        __syncthreads();
        int ebase = tile * T_TILE;
        #pragma unroll 4
        for (int it = 0; it < T_TILE / 256; ++it) {
            int e = ebase + it * 256 + tid;
            if (e < E) {
                unsigned s = (unsigned)src[e];
                unsigned d = (unsigned)dst[e];
                int pos = atomicAdd(&basec[s >> SRCB_BITS], 1);
                pkA[pos] = (d << SRCB_BITS) | (s & (SRCW - 1u));
            }
        }
        __syncthreads();
    }
}

// extract segment bases (tiny): baseA[SB+1], baseB[B+1]
__global__ void extract_bases(const int* __restrict__ cntA, int ntA, int SB,
                              const int* __restrict__ cntB, int ntB, int B,
                              int* __restrict__ baseA, int* __restrict__ baseB, int E) {
    int t = threadIdx.x;
    if (t < SB) baseA[t] = cntA[(size_t)t * ntA];
    if (t == SB) baseA[SB] = E;
    for (int l = t; l < B; l += blockDim.x) baseB[l] = cntB[(size_t)l * ntB];
    if (t == 0) baseB[B] = E;
}

// ---------------- pass B: bucket by dst (input already src-sorted) ----------------

__global__ void tilecountB(const unsigned* __restrict__ pkA, int* __restrict__ cntB,
                           int ntB, int E, int B) {
    __shared__ int hist[512];
    int blk = blockIdx.x, tid = threadIdx.x;
    hist[tid] = 0; hist[tid + 256] = 0;
    __syncthreads();
    int base = blk * T_TILE;
    #pragma unroll 4
    for (int it = 0; it < T_TILE / 256; ++it) {
        int e = base + it * 256 + tid;
        if (e < E) atomicAdd(&hist[(pkA[e] >> SRCB_BITS) >> NPB_BITS], 1);
    }
    __syncthreads();
    for (int l = tid; l < B; l += 256)
        cntB[(size_t)l * ntB + blk] = hist[l];
}

__global__ void scatterB(const unsigned* __restrict__ pkA, const int* __restrict__ cntB,
                         const int* __restrict__ baseA, unsigned* __restrict__ pk32,
                         int ntB, int E, int B, int SB, int tilesPerBlk) {
    __shared__ int basec[512];
    __shared__ int sbase[64];
    int tid = threadIdx.x;
    if (tid < SB + 1) sbase[tid] = baseA[tid];
    int t0 = blockIdx.x * tilesPerBlk;
    for (int tt = 0; tt < tilesPerBlk; ++tt) {
        int tile = t0 + tt;
        if (tile >= ntB) return;
        for (int l = tid; l < B; l += 256)
            basec[l] = cntB[(size_t)l * ntB + tile];
        __syncthreads();
        int ebase = tile * T_TILE;
        #pragma unroll 4
        for (int it = 0; it < T_TILE / 256; ++it) {
            int e = ebase + it * 256 + tid;
            if (e < E) {
                unsigned p = pkA[e];
                unsigned d = p >> SRCB_BITS;
                // recover src window by binary search over sbase
                int lo = 0, hi = SB;
                while (hi - lo > 1) {
                    int mid = (lo + hi) >> 1;
                    if (sbase[mid] <= e) lo = mid; else hi = mid;
                }
                unsigned s = ((unsigned)lo << SRCB_BITS) | (p & (SRCW - 1u));
                int pos = atomicAdd(&basec[d >> NPB_BITS], 1);
                pk32[pos] = (d & (NPB - 1u)) | (s << NPB_BITS);
            }
        }
        __syncthreads();
    }
}

// ---------------- per-bucket node prep: deg -> dinv, z1 = x*dinv ----------------

__global__ void __launch_bounds__(1024)
degz1(const int* __restrict__ baseB, const unsigned* __restrict__ pk,
      const float* __restrict__ x, float* __restrict__ dinv, float* __restrict__ z1,
      int N) {
    __shared__ int cnt[NPB];
    int b = blockIdx.x, tid = threadIdx.x;
    int base = baseB[b], n = baseB[b + 1] - base;
    cnt[tid] = 0;
    __syncthreads();
    int k0 = 0;
    for (; k0 + 8192 <= n; k0 += 8192) {
        unsigned p[8];
        #pragma unroll
        for (int u = 0; u < 8; ++u) p[u] = pk[base + k0 + tid + u * 1024];
        #pragma unroll
        for (int u = 0; u < 8; ++u) atomicAdd(&cnt[p[u] & (NPB - 1u)], 1);
    }
    for (int k = k0 + tid; k < n; k += 1024)
        atomicAdd(&cnt[pk[base + k] & (NPB - 1u)], 1);
    __syncthreads();
    int i = (b << NPB_BITS) + tid;
    if (i < N) {
        float di = rsqrtf((float)cnt[tid] + 1.0f);
        dinv[i] = di;
        float2 xv = ((const float2*)x)[i];
        ((float2*)z1)[i] = make_float2(xv.x * di, xv.y * di);
    }
}

// ---------------- layers: LDS accumulate + fused node epilogue ----------------

__global__ void __launch_bounds__(1024)
layer1(const int* __restrict__ baseB, const unsigned* __restrict__ pk,
       const float* __restrict__ z1, const float* __restrict__ W1,
       const float* __restrict__ b1, const float* __restrict__ dinv,
       float* __restrict__ z2, int N) {
    __shared__ float acc[NPB * 3];   // stride 3: banks (3d+c)%32 uniform
    int b = blockIdx.x, tid = threadIdx.x;
    int base = baseB[b], n = baseB[b + 1] - base;
    #pragma unroll
    for (int j = 0; j < 3; ++j) acc[tid + j * 1024] = 0.f;
    __syncthreads();
    const float2* z = (const float2*)z1;
    int k0 = 0;
    for (; k0 + 8192 <= n; k0 += 8192) {
        unsigned p[8]; float2 v[8];
        #pragma unroll
        for (int u = 0; u < 8; ++u) p[u] = pk[base + k0 + tid + u * 1024];
        #pragma unroll
        for (int u = 0; u < 8; ++u) v[u] = z[p[u] >> NPB_BITS];
        #pragma unroll
        for (int u = 0; u < 8; ++u) {
            int d = (int)(p[u] & (NPB - 1u)) * 3;
            atomicAdd(&acc[d + 0], v[u].x);
            atomicAdd(&acc[d + 1], v[u].y);
        }
    }
    for (int k = k0 + tid; k < n; k += 1024) {
        unsigned p = pk[base + k];
        float2 v = z[p >> NPB_BITS];
        int d = (int)(p & (NPB - 1u)) * 3;
        atomicAdd(&acc[d + 0], v.x);
        atomicAdd(&acc[d + 1], v.y);
    }
    __syncthreads();
    int i = (b << NPB_BITS) + tid;
    if (i < N) {
        float di = dinv[i];
        float2 zi = z[i];
        float g0 = di * (acc[tid * 3 + 0] + zi.x);
        float g1 = di * (acc[tid * 3 + 1] + zi.y);
        float4 o;
        o.x = di * tanhf(fmaf(g0, W1[0], fmaf(g1, W1[4], b1[0])));
        o.y = di * tanhf(fmaf(g0, W1[1], fmaf(g1, W1[5], b1[1])));
        o.z = di * tanhf(fmaf(g0, W1[2], fmaf(g1, W1[6], b1[2])));
        o.w = di * tanhf(fmaf(g0, W1[3], fmaf(g1, W1[7], b1[3])));
        ((float4*)z2)[i] = o;
    }
}

__global__ void __launch_bounds__(1024)
layer2(const int* __restrict__ baseB, const unsigned* __restrict__ pk,
       const float* __restrict__ z2, const float* __restrict__ W2,
       const float* __restrict__ b2, const float* __restrict__ W3,
       const float* __restrict__ dinv, float* __restrict__ z3, int N) {
    __shared__ float acc[NPB * 5];   // stride 5: banks (5d+c)%32 uniform
    int b = blockIdx.x, tid = threadIdx.x;
    int base = baseB[b], n = baseB[b + 1] - base;
    #pragma unroll
    for (int j = 0; j < 5; ++j) acc[tid + j * 1024] = 0.f;
    __syncthreads();
    const float4* z = (const float4*)z2;
    int k0 = 0;
    for (; k0 + 8192 <= n; k0 += 8192) {
        unsigned p[8]; float4 v[8];
        #pragma unroll
        for (int u = 0; u < 8; ++u) p[u] = pk[base + k0 + tid + u * 1024];
        #pragma unroll
        for (int u = 0; u < 8; ++u) v[u] = z[p[u] >> NPB_BITS];
        #pragma unroll
        for (int u = 0; u < 8; ++u) {
            int d = (int)(p[u] & (NPB - 1u)) * 5;
            atomicAdd(&acc[d + 0], v[u].x);
            atomicAdd(&acc[d + 1], v[u].y);
            atomicAdd(&acc[d + 2], v[u].z);
            atomicAdd(&acc[d + 3], v[u].w);
        }
    }
    for (int k = k0 + tid; k < n; k += 1024) {
        unsigned p = pk[base + k];
        float4 v = z[p >> NPB_BITS];
        int d = (int)(p & (NPB - 1u)) * 5;
        atomicAdd(&acc[d + 0], v.x);
        atomicAdd(&acc[d + 1], v.y);
        atomicAdd(&acc[d + 2], v.z);
        atomicAdd(&acc[d + 3], v.w);
    }
    __syncthreads();
    int i = (b << NPB_BITS) + tid;
    if (i < N) {
        float di = dinv[i];
        float4 zi = z[i];
        float g0 = di * (acc[tid * 5 + 0] + zi.x);
        float g1 = di * (acc[tid * 5 + 1] + zi.y);
        float g2 = di * (acc[tid * 5 + 2] + zi.z);
        float g3 = di * (acc[tid * 5 + 3] + zi.w);
        float h[4];
        #pragma unroll
        for (int c = 0; c < 4; ++c)
            h[c] = tanhf(b2[c] + g0 * W2[c] + g1 * W2[4 + c] + g2 * W2[8 + c] + g3 * W2[12 + c]);
        float v0 = h[0] * W3[0] + h[1] * W3[2] + h[2] * W3[4] + h[3] * W3[6];
        float v1 = h[0] * W3[1] + h[1] * W3[3] + h[2] * W3[5] + h[3] * W3[7];
        ((float2*)z3)[i] = make_float2(v0 * di, v1 * di);
    }
}

__global__ void __launch_bounds__(1024)
layer3(const int* __restrict__ baseB, const unsigned* __restrict__ pk,
       const float* __restrict__ z3, const float* __restrict__ b3,
       const float* __restrict__ dinv, float* __restrict__ out, int N) {
    __shared__ float acc[NPB * 3];
    int b = blockIdx.x, tid = threadIdx.x;
    int base = baseB[b], n = baseB[b + 1] - base;
    #pragma unroll
    for (int j = 0; j < 3; ++j) acc[tid + j * 1024] = 0.f;
    __syncthreads();
    const float2* z = (const float2*)z3;
    int k0 = 0;
    for (; k0 + 8192 <= n; k0 += 8192) {
        unsigned p[8]; float2 v[8];
        #pragma unroll
        for (int u = 0; u < 8; ++u) p[u] = pk[base + k0 + tid + u * 1024];
        #pragma unroll
        for (int u = 0; u < 8; ++u) v[u] = z[p[u] >> NPB_BITS];
        #pragma unroll
        for (int u = 0; u < 8; ++u) {
            int d = (int)(p[u] & (NPB - 1u)) * 3;
            atomicAdd(&acc[d + 0], v[u].x);
            atomicAdd(&acc[d + 1], v[u].y);
        }
    }
    for (int k = k0 + tid; k < n; k += 1024) {
        unsigned p = pk[base + k];
        float2 v = z[p >> NPB_BITS];
        int d = (int)(p & (NPB - 1u)) * 3;
        atomicAdd(&acc[d + 0], v.x);
        atomicAdd(&acc[d + 1], v.y);
    }
    __syncthreads();
    int i = (b << NPB_BITS) + tid;
    if (i < N) {
        float di = dinv[i];
        float2 zi = z[i];
        ((float2*)out)[i] = make_float2(fmaf(di, acc[tid * 3 + 0] + zi.x, b3[0]),
                                        fmaf(di, acc[tid * 3 + 1] + zi.y, b3[1]));
    }
}

extern "C" void kernel_launch(void* const* d_in, const int* in_sizes, int n_in,
                              void* d_out, int out_size, void* d_ws, size_t ws_size,
                              hipStream_t stream) {
    const float* x  = (const float*)d_in[0];
    const int*   ei = (const int*)d_in[1];
    const float* W1 = (const float*)d_in[2];
    const float* b1 = (const float*)d_in[3];
    const float* W2 = (const float*)d_in[4];
    const float* b2 = (const float*)d_in[5];
    const float* W3 = (const float*)d_in[6];
    const float* b3 = (const float*)d_in[7];
    float* out = (float*)d_out;

    const int N = in_sizes[0] / 2;
    const int E = in_sizes[1] / 2;
    const int* src = ei;
    const int* dst = ei + E;

    const int B  = (N + NPB - 1) >> NPB_BITS;        // 489 dst buckets
    const int SB = (N + SRCW - 1) >> SRCB_BITS;      // 62 src windows
    const int ntiles = (E + T_TILE - 1) / T_TILE;    // 1954
    const int mlenA = SB * ntiles;                   // ~121K
    const int mlenB = B * ntiles;                    // ~955K
    const int NBA = (mlenA + 1023) / 1024;
    const int NBB = (mlenB + 1023) / 1024;
    const int SCAT_BLOCKS = 512;
    const int tilesPerBlk = (ntiles + SCAT_BLOCKS - 1) / SCAT_BLOCKS;

    // ws layout (256B-aligned): 9N*4 + mlenA + mlenB + 2E*4 + small ~ 151MB
    auto align = [](size_t o) { return (o + 255) & ~(size_t)255; };
    char* base = (char*)d_ws;
    size_t off = 0;
    float*    dinv   = (float*)(base + off);    off = align(off + (size_t)N * 4);
    float*    z1     = (float*)(base + off);    off = align(off + (size_t)2 * N * 4);
    float*    z2     = (float*)(base + off);    off = align(off + (size_t)4 * N * 4);
    float*    z3     = (float*)(base + off);    off = align(off + (size_t)2 * N * 4);
    int*      bsum   = (int*)(base + off);      off = align(off + (size_t)1024 * 4);
    int*      baseA  = (int*)(base + off);      off = align(off + (size_t)64 * 4);
    int*      baseB  = (int*)(base + off);      off = align(off + (size_t)(B + 1) * 4);
    int*      cntA   = (int*)(base + off);      off = align(off + (size_t)mlenA * 4);
    unsigned* pkA    = (unsigned*)(base + off); off = align(off + (size_t)E * 4);
    unsigned* pk32   = (unsigned*)(base + off); off = align(off + (size_t)E * 4);
    int*      cntB   = (int*)z2;                // overlay: 8MB >= mlenB*4B=3.8MB;
                                                // last read in scatterB, z2 written by layer1

    dim3 blk(TPB);
    tilecountA<<<dim3(ntiles), blk, 0, stream>>>(src, cntA, ntiles, E, SB);
    scan_k1<<<dim3(NBA), blk, 0, stream>>>(cntA, bsum, mlenA);
    scan_k2<<<dim3(1), dim3(1024), 0, stream>>>(bsum, NBA);
    scan_k3<<<dim3(NBA), blk, 0, stream>>>(cntA, bsum, mlenA);
    scatterA<<<dim3(SCAT_BLOCKS), blk, 0, stream>>>(src, dst, cntA, pkA, ntiles, E, SB,
                                                    tilesPerBlk);
    tilecountB<<<dim3(ntiles), blk, 0, stream>>>(pkA, cntB, ntiles, E, B);
    scan_k1<<<dim3(NBB), blk, 0, stream>>>(cntB, bsum, mlenB);
    scan_k2<<<dim3(1), dim3(1024), 0, stream>>>(bsum, NBB);
    scan_k3<<<dim3(NBB), blk, 0, stream>>>(cntB, bsum, mlenB);
    extract_bases<<<dim3(1), dim3(512), 0, stream>>>(cntA, ntiles, SB, cntB, ntiles, B,
                                                     baseA, baseB, E);
    scatterB<<<dim3(SCAT_BLOCKS), blk, 0, stream>>>(pkA, cntB, baseA, pk32, ntiles, E,
                                                    B, SB, tilesPerBlk);
    degz1<<<dim3(B), dim3(1024), 0, stream>>>(baseB, pk32, x, dinv, z1, N);
    layer1<<<dim3(B), dim3(1024), 0, stream>>>(baseB, pk32, z1, W1, b1, dinv, z2, N);
    layer2<<<dim3(B), dim3(1024), 0, stream>>>(baseB, pk32, z2, W2, b2, W3, dinv, z3, N);
    layer3<<<dim3(B), dim3(1024), 0, stream>>>(baseB, pk32, z3, b3, dinv, out, N);
}

// Round 8
// 954.453 us; speedup vs baseline: 1.2321x; 1.2321x over previous
//
#include <hip/hip_runtime.h>

// GCN 3-layer. Single-pass dst-bucket sort (256-node buckets) + in-LDS
// counting sort per bucket -> fully dst-sorted edge list; layers do
// wave-segmented reduction (shfl scan) with ~3 LDS atomic tail-writes per
// 64-edge group instead of per-edge fp32 atomics (R6/R7 showed per-edge LDS
// atomics cost ~3.4cyc/lane and bound layer2 at 345us regardless of traffic).
// Math per layer (input u): z = u*dinv; s_i = sum_{e:dst=i} z[src_e];
//   out_i = (dinv_i*(s_i + z_i)) @ W + b   (self-loop folds into s+z).
// pk32 = (dst&255) | (src<<8)  (src < 2^19 -> 27 bits).
// Segmented scan + atomic tail-write is correct for ANY in-bucket order, so
// sortbuild's LDS-capacity fallback (leave bucket unsorted) is safe.

#define TPB 256
#define T_TILE 32768
#define NPB 256
#define NPB_BITS 8
#define ELDS_CAP 10752   // mean bucket 8188 edges, sigma ~90 -> +28 sigma

// ---------------- dst-bucket histogram per tile ----------------

__global__ void tilecountB(const int* __restrict__ dst, int* __restrict__ cntB,
                           int ntB, int E, int B) {
    __shared__ int hist[2048];
    int blk = blockIdx.x, tid = threadIdx.x;
    for (int l = tid; l < 2048; l += 256) hist[l] = 0;
    __syncthreads();
    int base = blk * T_TILE;
    #pragma unroll 8
    for (int it = 0; it < T_TILE / 256; ++it) {
        int e = base + it * 256 + tid;
        if (e < E) atomicAdd(&hist[((unsigned)dst[e]) >> NPB_BITS], 1);
    }
    __syncthreads();
    for (int l = tid; l < B; l += 256)
        cntB[(size_t)l * ntB + blk] = hist[l];
}

// ---- 3-kernel exclusive scan over data[len] (in-place), 1024 elems/block ----
__global__ void scan_k1(const int* __restrict__ data, int* __restrict__ bsum, int len) {
    __shared__ int lds[TPB];
    int b = blockIdx.x, t = threadIdx.x;
    int base = b * 1024 + t * 4;
    int s = 0;
    #pragma unroll
    for (int j = 0; j < 4; ++j) { int i = base + j; if (i < len) s += data[i]; }
    lds[t] = s; __syncthreads();
    for (int off = 128; off > 0; off >>= 1) {
        if (t < off) lds[t] += lds[t + off];
        __syncthreads();
    }
    if (t == 0) bsum[b] = lds[0];
}

__global__ void scan_k2(int* __restrict__ bsum, int NB) {
    __shared__ int lds[1024];
    int t = threadIdx.x;
    int v = (t < NB) ? bsum[t] : 0;
    lds[t] = v; __syncthreads();
    for (int off = 1; off < 1024; off <<= 1) {
        int add = (t >= off) ? lds[t - off] : 0;
        __syncthreads();
        lds[t] += add;
        __syncthreads();
    }
    if (t < NB) bsum[t] = lds[t] - v;  // exclusive
}

__global__ void scan_k3(int* __restrict__ data, const int* __restrict__ bsum, int len) {
    __shared__ int lds[TPB];
    int b = blockIdx.x, t = threadIdx.x;
    int base = b * 1024 + t * 4;
    int v[4]; int s = 0;
    #pragma unroll
    for (int j = 0; j < 4; ++j) { int i = base + j; v[j] = (i < len) ? data[i] : 0; s += v[j]; }
    int orig = s;
    lds[t] = s; __syncthreads();
    for (int off = 1; off < 256; off <<= 1) {
        int add = (t >= off) ? lds[t - off] : 0;
        __syncthreads();
        lds[t] += add;
        __syncthreads();
    }
    int run = bsum[b] + lds[t] - orig;
    #pragma unroll
    for (int j = 0; j < 4; ++j) {
        int i = base + j;
        if (i < len) { data[i] = run; run += v[j]; }
    }
}

__global__ void extract_bases(const int* __restrict__ cntB, int ntB, int B,
                              int* __restrict__ baseB, int E) {
    int t = threadIdx.x;
    for (int l = t; l < B; l += blockDim.x) baseB[l] = cntB[(size_t)l * ntB];
    if (t == 0) baseB[B] = E;
}

// one block per tile; per-tile cursor bases precomputed -> deterministic
__global__ void scatterB(const int* __restrict__ dst, const int* __restrict__ src,
                         const int* __restrict__ cntB, unsigned* __restrict__ pk32,
                         int ntB, int E, int B) {
    __shared__ int basec[2048];
    int tile = blockIdx.x, tid = threadIdx.x;
    for (int l = tid; l < B; l += 256)
        basec[l] = cntB[(size_t)l * ntB + tile];
    __syncthreads();
    int ebase = tile * T_TILE;
    #pragma unroll 8
    for (int it = 0; it < T_TILE / 256; ++it) {
        int e = ebase + it * 256 + tid;
        if (e < E) {
            unsigned d = (unsigned)dst[e];
            unsigned s = (unsigned)src[e];
            int pos = atomicAdd(&basec[d >> NPB_BITS], 1);
            pk32[pos] = (d & (NPB - 1u)) | (s << NPB_BITS);
        }
    }
}

// ---------------- per-bucket in-LDS counting sort + dinv/z1 ----------------

__global__ void __launch_bounds__(256)
sortbuild(const int* __restrict__ baseB_, unsigned* __restrict__ pk,
          const float* __restrict__ x, float* __restrict__ dinv,
          float* __restrict__ z1, int N) {
    __shared__ int cnt[NPB];
    __shared__ int tmp[NPB];
    __shared__ int cur[NPB];
    __shared__ unsigned eb[ELDS_CAP];
    int b = blockIdx.x, tid = threadIdx.x;
    int base = baseB_[b], n = baseB_[b + 1] - base;
    cnt[tid] = 0;
    __syncthreads();
    int k0 = 0;
    for (; k0 + 2048 <= n; k0 += 2048) {
        unsigned p[8];
        #pragma unroll
        for (int u = 0; u < 8; ++u) p[u] = pk[base + k0 + tid + u * 256];
        #pragma unroll
        for (int u = 0; u < 8; ++u) atomicAdd(&cnt[p[u] & (NPB - 1u)], 1);
    }
    for (int k = k0 + tid; k < n; k += 256)
        atomicAdd(&cnt[pk[base + k] & (NPB - 1u)], 1);
    __syncthreads();
    int c = cnt[tid];
    tmp[tid] = c; __syncthreads();
    for (int o = 1; o < 256; o <<= 1) {
        int a = (tid >= o) ? tmp[tid - o] : 0;
        __syncthreads();
        tmp[tid] += a;
        __syncthreads();
    }
    cur[tid] = tmp[tid] - c;  // exclusive prefix
    int i = (b << NPB_BITS) + tid;
    if (i < N) {
        float di = rsqrtf((float)c + 1.0f);
        dinv[i] = di;
        float2 xv = ((const float2*)x)[i];
        ((float2*)z1)[i] = make_float2(xv.x * di, xv.y * di);
    }
    __syncthreads();
    if (n <= ELDS_CAP) {
        k0 = 0;
        for (; k0 + 2048 <= n; k0 += 2048) {
            unsigned p[8];
            #pragma unroll
            for (int u = 0; u < 8; ++u) p[u] = pk[base + k0 + tid + u * 256];
            #pragma unroll
            for (int u = 0; u < 8; ++u) {
                int pos = atomicAdd(&cur[p[u] & (NPB - 1u)], 1);
                eb[pos] = p[u];
            }
        }
        for (int k = k0 + tid; k < n; k += 256) {
            unsigned p = pk[base + k];
            int pos = atomicAdd(&cur[p & (NPB - 1u)], 1);
            eb[pos] = p;
        }
        __syncthreads();
        for (int k = tid; k < n; k += 256) pk[base + k] = eb[k];
    }
    // else: bucket stays unsorted -- layers remain correct (seg-scan + atomic
    // tails handles any order), just more tail-writes for this rare bucket.
}

// ---------------- layers: wave-segmented reduction ----------------

__global__ void __launch_bounds__(256)
layer1(const int* __restrict__ baseB_, const unsigned* __restrict__ pk,
       const float* __restrict__ z1, const float* __restrict__ W1,
       const float* __restrict__ b1, const float* __restrict__ dinv,
       float* __restrict__ z2, int N) {
    __shared__ float acc[NPB * 3];
    int b = blockIdx.x, tid = threadIdx.x;
    int base = baseB_[b], n = baseB_[b + 1] - base;
    #pragma unroll
    for (int j = 0; j < 3; ++j) acc[tid + j * 256] = 0.f;
    __syncthreads();
    const float2* z = (const float2*)z1;
    int lane = tid & 63, wv = tid >> 6;
    int G = (n + 63) >> 6;
    for (int g = wv; g < G; g += 4) {
        int k = (g << 6) + lane;
        int d; float s0, s1;
        if (k < n) {
            unsigned p = pk[base + k];
            d = (int)(p & (NPB - 1u));
            float2 v = z[p >> NPB_BITS];
            s0 = v.x; s1 = v.y;
        } else { d = NPB; s0 = 0.f; s1 = 0.f; }
        int dp = __shfl_up(d, 1);
        unsigned f = (lane == 0 || d != dp) ? 1u : 0u;
        #pragma unroll
        for (int o = 1; o < 64; o <<= 1) {
            float t0 = __shfl_up(s0, o), t1 = __shfl_up(s1, o);
            unsigned fu = __shfl_up(f, o);
            if (lane >= o) { if (!f) { s0 += t0; s1 += t1; } f |= fu; }
        }
        int dn = __shfl_down(d, 1);
        bool tail = (lane == 63) || (d != dn);
        if (tail && d < NPB) {
            atomicAdd(&acc[d * 3 + 0], s0);
            atomicAdd(&acc[d * 3 + 1], s1);
        }
    }
    __syncthreads();
    int i = (b << NPB_BITS) + tid;
    if (i < N) {
        float di = dinv[i];
        float2 zi = z[i];
        float g0 = di * (acc[tid * 3 + 0] + zi.x);
        float g1 = di * (acc[tid * 3 + 1] + zi.y);
        float4 o;
        o.x = di * tanhf(fmaf(g0, W1[0], fmaf(g1, W1[4], b1[0])));
        o.y = di * tanhf(fmaf(g0, W1[1], fmaf(g1, W1[5], b1[1])));
        o.z = di * tanhf(fmaf(g0, W1[2], fmaf(g1, W1[6], b1[2])));
        o.w = di * tanhf(fmaf(g0, W1[3], fmaf(g1, W1[7], b1[3])));
        ((float4*)z2)[i] = o;
    }
}

__global__ void __launch_bounds__(256)
layer2(const int* __restrict__ baseB_, const unsigned* __restrict__ pk,
       const float* __restrict__ z2, const float* __restrict__ W2,
       const float* __restrict__ b2, const float* __restrict__ W3,
       const float* __restrict__ dinv, float* __restrict__ z3, int N) {
    __shared__ float acc[NPB * 5];
    int b = blockIdx.x, tid = threadIdx.x;
    int base = baseB_[b], n = baseB_[b + 1] - base;
    #pragma unroll
    for (int j = 0; j < 5; ++j) acc[tid + j * 256] = 0.f;
    __syncthreads();
    const float4* z = (const float4*)z2;
    int lane = tid & 63, wv = tid >> 6;
    int G = (n + 63) >> 6;
    for (int g = wv; g < G; g += 4) {
        int k = (g << 6) + lane;
        int d; float s0, s1, s2, s3;
        if (k < n) {
            unsigned p = pk[base + k];
            d = (int)(p & (NPB - 1u));
            float4 v = z[p >> NPB_BITS];
            s0 = v.x; s1 = v.y; s2 = v.z; s3 = v.w;
        } else { d = NPB; s0 = s1 = s2 = s3 = 0.f; }
        int dp = __shfl_up(d, 1);
        unsigned f = (lane == 0 || d != dp) ? 1u : 0u;
        #pragma unroll
        for (int o = 1; o < 64; o <<= 1) {
            float t0 = __shfl_up(s0, o), t1 = __shfl_up(s1, o);
            float t2 = __shfl_up(s2, o), t3 = __shfl_up(s3, o);
            unsigned fu = __shfl_up(f, o);
            if (lane >= o) {
                if (!f) { s0 += t0; s1 += t1; s2 += t2; s3 += t3; }
                f |= fu;
            }
        }
        int dn = __shfl_down(d, 1);
        bool tail = (lane == 63) || (d != dn);
        if (tail && d < NPB) {
            atomicAdd(&acc[d * 5 + 0], s0);
            atomicAdd(&acc[d * 5 + 1], s1);
            atomicAdd(&acc[d * 5 + 2], s2);
            atomicAdd(&acc[d * 5 + 3], s3);
        }
    }
    __syncthreads();
    int i = (b << NPB_BITS) + tid;
    if (i < N) {
        float di = dinv[i];
        float4 zi = z[i];
        float g0 = di * (acc[tid * 5 + 0] + zi.x);
        float g1 = di * (acc[tid * 5 + 1] + zi.y);
        float g2 = di * (acc[tid * 5 + 2] + zi.z);
        float g3 = di * (acc[tid * 5 + 3] + zi.w);
        float h[4];
        #pragma unroll
        for (int c = 0; c < 4; ++c)
            h[c] = tanhf(b2[c] + g0 * W2[c] + g1 * W2[4 + c] + g2 * W2[8 + c] + g3 * W2[12 + c]);
        float v0 = h[0] * W3[0] + h[1] * W3[2] + h[2] * W3[4] + h[3] * W3[6];
        float v1 = h[0] * W3[1] + h[1] * W3[3] + h[2] * W3[5] + h[3] * W3[7];
        ((float2*)z3)[i] = make_float2(v0 * di, v1 * di);
    }
}

__global__ void __launch_bounds__(256)
layer3(const int* __restrict__ baseB_, const unsigned* __restrict__ pk,
       const float* __restrict__ z3, const float* __restrict__ b3,
       const float* __restrict__ dinv, float* __restrict__ out, int N) {
    __shared__ float acc[NPB * 3];
    int b = blockIdx.x, tid = threadIdx.x;
    int base = baseB_[b], n = baseB_[b + 1] - base;
    #pragma unroll
    for (int j = 0; j < 3; ++j) acc[tid + j * 256] = 0.f;
    __syncthreads();
    const float2* z = (const float2*)z3;
    int lane = tid & 63, wv = tid >> 6;
    int G = (n + 63) >> 6;
    for (int g = wv; g < G; g += 4) {
        int k = (g << 6) + lane;
        int d; float s0, s1;
        if (k < n) {
            unsigned p = pk[base + k];
            d = (int)(p & (NPB - 1u));
            float2 v = z[p >> NPB_BITS];
            s0 = v.x; s1 = v.y;
        } else { d = NPB; s0 = 0.f; s1 = 0.f; }
        int dp = __shfl_up(d, 1);
        unsigned f = (lane == 0 || d != dp) ? 1u : 0u;
        #pragma unroll
        for (int o = 1; o < 64; o <<= 1) {
            float t0 = __shfl_up(s0, o), t1 = __shfl_up(s1, o);
            unsigned fu = __shfl_up(f, o);
            if (lane >= o) { if (!f) { s0 += t0; s1 += t1; } f |= fu; }
        }
        int dn = __shfl_down(d, 1);
        bool tail = (lane == 63) || (d != dn);
        if (tail && d < NPB) {
            atomicAdd(&acc[d * 3 + 0], s0);
            atomicAdd(&acc[d * 3 + 1], s1);
        }
    }
    __syncthreads();
    int i = (b << NPB_BITS) + tid;
    if (i < N) {
        float di = dinv[i];
        float2 zi = z[i];
        ((float2*)out)[i] = make_float2(fmaf(di, acc[tid * 3 + 0] + zi.x, b3[0]),
                                        fmaf(di, acc[tid * 3 + 1] + zi.y, b3[1]));
    }
}

extern "C" void kernel_launch(void* const* d_in, const int* in_sizes, int n_in,
                              void* d_out, int out_size, void* d_ws, size_t ws_size,
                              hipStream_t stream) {
    const float* x  = (const float*)d_in[0];
    const int*   ei = (const int*)d_in[1];
    const float* W1 = (const float*)d_in[2];
    const float* b1 = (const float*)d_in[3];
    const float* W2 = (const float*)d_in[4];
    const float* b2 = (const float*)d_in[5];
    const float* W3 = (const float*)d_in[6];
    const float* b3 = (const float*)d_in[7];
    float* out = (float*)d_out;

    const int N = in_sizes[0] / 2;
    const int E = in_sizes[1] / 2;
    const int* src = ei;
    const int* dst = ei + E;

    const int B = (N + NPB - 1) >> NPB_BITS;         // 1954 buckets of 256 nodes
    const int ntB = (E + T_TILE - 1) / T_TILE;       // 489 tiles of 32K edges
    const int mlen = B * ntB;                        // ~955K
    const int NB = (mlen + 1023) / 1024;             // <=1024

    // ws layout (256B-aligned). cntB overlays z2 (z2 first written by layer1,
    // cntB last read by scatterB).
    auto align = [](size_t o) { return (o + 255) & ~(size_t)255; };
    char* wbase = (char*)d_ws;
    size_t off = 0;
    float*    dinv  = (float*)(wbase + off);    off = align(off + (size_t)N * 4);
    float*    z1    = (float*)(wbase + off);    off = align(off + (size_t)2 * N * 4);
    float*    z2    = (float*)(wbase + off);    off = align(off + (size_t)4 * N * 4);
    float*    z3    = (float*)(wbase + off);    off = align(off + (size_t)2 * N * 4);
    int*      bsum  = (int*)(wbase + off);      off = align(off + (size_t)1024 * 4);
    int*      baseB = (int*)(wbase + off);      off = align(off + (size_t)(B + 1) * 4);
    unsigned* pk32  = (unsigned*)(wbase + off); off = align(off + (size_t)E * 4);
    int*      cntB  = (int*)z2;                 // 3.8MB <= 8MB overlay

    dim3 blk(TPB);
    tilecountB<<<dim3(ntB), blk, 0, stream>>>(dst, cntB, ntB, E, B);
    scan_k1<<<dim3(NB), blk, 0, stream>>>(cntB, bsum, mlen);
    scan_k2<<<dim3(1), dim3(1024), 0, stream>>>(bsum, NB);
    scan_k3<<<dim3(NB), blk, 0, stream>>>(cntB, bsum, mlen);
    extract_bases<<<dim3(1), dim3(1024), 0, stream>>>(cntB, ntB, B, baseB, E);
    scatterB<<<dim3(ntB), blk, 0, stream>>>(dst, src, cntB, pk32, ntB, E, B);
    sortbuild<<<dim3(B), blk, 0, stream>>>(baseB, pk32, x, dinv, z1, N);
    layer1<<<dim3(B), blk, 0, stream>>>(baseB, pk32, z1, W1, b1, dinv, z2, N);
    layer2<<<dim3(B), blk, 0, stream>>>(baseB, pk32, z2, W2, b2, W3, dinv, z3, N);
    layer3<<<dim3(B), blk, 0, stream>>>(baseB, pk32, z3, b3, dinv, out, N);
}